// Round 12
// baseline (159.902 us; speedup 1.0000x reference)
//
#include <hip/hip_runtime.h>
#include <hip/hip_bf16.h>

#define N_PTS 4096
#define D_EMB 64
#define BT    64                                   // block tile (4 waves x 32x32)
#define NPART ((N_PTS / BT) * (N_PTS / BT))        // 4096 block partials

typedef __attribute__((ext_vector_type(8))) short bf16x8;  // 8 bf16 = 4 VGPR
typedef __attribute__((ext_vector_type(4))) float f32x4;   // MFMA 16x16 acc

// ---------------------------------------------------------------------------
// Fused prep: bf16 hi/lo split + exact f32 row squared-norms.
// ---------------------------------------------------------------------------
__global__ void prep_kernel(const float* __restrict__ mapping,
                            ushort* __restrict__ Mhi,
                            ushort* __restrict__ Mlo,
                            float* __restrict__ nrm) {
  const int row = blockIdx.x;
  const int l = threadIdx.x;          // 0..63
  const int idx = row * D_EMB + l;
  const float x = mapping[idx];
  __hip_bfloat16 h = __float2bfloat16(x);
  const float hf = __bfloat162float(h);
  __hip_bfloat16 lo = __float2bfloat16(x - hf);
  Mhi[idx] = *reinterpret_cast<ushort*>(&h);
  Mlo[idx] = *reinterpret_cast<ushort*>(&lo);
  float s = x * x;
  #pragma unroll
  for (int off = 32; off > 0; off >>= 1) s += __shfl_down(s, off);
  if (l == 0) nrm[row] = s;
}

// ---------------------------------------------------------------------------
// DIAGNOSTIC ROUND. Template of R11's main:
//   MODE 0: full body (epilogue + partial write) — production when REPS=1.
//   MODE 1: gram-only — staging, D-reg loads, MFMA, LDS dump, then an
//           anti-DCE consume (rule 17) instead of the epilogue.
// REPS>1 repeats the whole body identically (deterministic); an
// asm memory clobber per rep forces real re-issue of every load, making
// the probe visible in rocprof's top-5 (harness poison fills are ~40us).
// ---------------------------------------------------------------------------
template <int MODE, int REPS>
__global__ __launch_bounds__(256) void distortion_main_t(
    const ushort* __restrict__ Mhi, const ushort* __restrict__ Mlo,
    const float* __restrict__ Dm, const float* __restrict__ nrm,
    double* __restrict__ part) {
  __shared__ __align__(16) char smem[32768];   // 4 panels; later gram dump
  ushort* span = (ushort*)smem;   // [p][r][cs]: p*4096 + r*64 + cs*8 (ushorts)
  float*  sg   = (float*)smem;    // gram dump: 64 rows x 64 cols f32 (16KB)

  const int t = threadIdx.x;
  const int w = t >> 6, l = t & 63;
  const int r16 = l & 15;        // fragment row/col within 16
  const int kg  = l >> 4;        // k-group 0..3
  const int wr = w >> 1, wc = w & 1;
  const int i0 = blockIdx.y * BT;
  const int j0 = blockIdx.x * BT;

  const int jc    = l & 15;      // float4 col-chunk 0..15
  const int isub  = l >> 4;      // row-within-iter 0..3
  const int gj0   = j0 + jc * 4;
  const int irow0 = w * 16;

  for (int rep = 0; rep < REPS; ++rep) {
    if (rep) __syncthreads();
    asm volatile("" ::: "memory");   // force re-issue of loads each rep

    // ---- (1) early dense D-tile + col-norms into registers
    float4 D4[4];
    #pragma unroll
    for (int it = 0; it < 4; ++it) {
      const int gi = i0 + irow0 + it * 4 + isub;
      D4[it] = *(const float4*)(Dm + (size_t)gi * N_PTS + gj0);
    }
    const float4 rB4 = *(const float4*)(nrm + gj0);

    // ---- (2) stage 4 panels (64r x 64 bf16): LDS linear, src c = cs^(r&7)
    #pragma unroll
    for (int q = 0; q < 8; ++q) {
      const int s  = q * 256 + t;      // 16B slot 0..2047
      const int p  = s >> 9;           // panel: 0 AH, 1 AL, 2 BH, 3 BL
      const int sp = s & 511;
      const int r  = sp >> 3;          // row 0..63
      const int cs = sp & 7;           // stored chunk
      const int c  = cs ^ (r & 7);     // source chunk (involution)
      const ushort* base = (p & 1) ? Mlo : Mhi;
      const int row = ((p < 2) ? i0 : j0) + r;
      const ushort* g = base + (size_t)row * D_EMB + c * 8;
      char* ldst = smem + q * 4096 + w * 1024;   // wave-uniform + lane*16
      __builtin_amdgcn_global_load_lds(
          (const __attribute__((address_space(1))) void*)g,
          (__attribute__((address_space(3))) void*)ldst, 16, 0, 0);
    }
    __syncthreads();   // (3) single drain of staging + D regs

    // ---- (4) gram: 32x32/wave, swapped operands (layouts HW-verified)
    f32x4 acc[2][2] = {};
    #pragma unroll
    for (int ks = 0; ks < 2; ++ks) {
      bf16x8 aH[2], aL[2], bH[2], bL[2];
      #pragma unroll
      for (int m = 0; m < 2; ++m) {
        const int r  = wr * 32 + m * 16 + r16;
        const int cs = (ks * 4 + kg) ^ (r & 7);
        aH[m] = *(const bf16x8*)(span + 0 * 4096 + r * 64 + cs * 8);
        aL[m] = *(const bf16x8*)(span + 1 * 4096 + r * 64 + cs * 8);
      }
      #pragma unroll
      for (int n = 0; n < 2; ++n) {
        const int r  = wc * 32 + n * 16 + r16;
        const int cs = (ks * 4 + kg) ^ (r & 7);
        bH[n] = *(const bf16x8*)(span + 2 * 4096 + r * 64 + cs * 8);
        bL[n] = *(const bf16x8*)(span + 3 * 4096 + r * 64 + cs * 8);
      }
      #pragma unroll
      for (int m = 0; m < 2; ++m)
        #pragma unroll
        for (int n = 0; n < 2; ++n) {
          acc[m][n] = __builtin_amdgcn_mfma_f32_16x16x32_bf16(
              bH[n], aH[m], acc[m][n], 0, 0, 0);   // Hj.Hi
          acc[m][n] = __builtin_amdgcn_mfma_f32_16x16x32_bf16(
              bH[n], aL[m], acc[m][n], 0, 0, 0);   // Hj.Li
          acc[m][n] = __builtin_amdgcn_mfma_f32_16x16x32_bf16(
              bL[n], aH[m], acc[m][n], 0, 0, 0);   // Lj.Hi
        }
    }
    __syncthreads();   // frag reads done -> panel space reusable

    // ---- (5) dump gram to LDS, slot swizzle jc4 ^ (i_b&7)
    #pragma unroll
    for (int m = 0; m < 2; ++m) {
      const int i_b = wr * 32 + m * 16 + r16;
      #pragma unroll
      for (int n = 0; n < 2; ++n) {
        const int jc4 = wc * 8 + n * 4 + kg;
        *(f32x4*)(sg + i_b * 64 + ((jc4 ^ (i_b & 7)) * 4)) = acc[m][n];
      }
    }
    __syncthreads();

    // ---- (6) epilogue (MODE 0) or anti-DCE consume (MODE 1)
    float s1 = 0.f, s2 = 0.f, s3 = 0.f, s4 = 0.f;
    if constexpr (MODE == 0) {
      #pragma unroll
      for (int it = 0; it < 4; ++it) {
        const int i_b = irow0 + it * 4 + isub;
        const int gi = i0 + i_b;
        const float rA = nrm[gi];
        const float4 g4 = *(const float4*)(sg + i_b * 64 + ((jc ^ (i_b & 7)) * 4));
        const float4 Dv4 = D4[it];
        #pragma unroll
        for (int r = 0; r < 4; ++r) {
          const float Dv  = (r == 0) ? Dv4.x : (r == 1) ? Dv4.y : (r == 2) ? Dv4.z : Dv4.w;
          const float rB  = (r == 0) ? rB4.x : (r == 1) ? rB4.y : (r == 2) ? rB4.z : rB4.w;
          const float dot = (r == 0) ? g4.x  : (r == 1) ? g4.y  : (r == 2) ? g4.z  : g4.w;
          const float sq = fmaxf(rA + rB - 2.f * dot, 0.f);
          float dd = __builtin_amdgcn_sqrtf(sq);
          const bool diag = (gi == gj0 + r);
          if (diag) dd = 0.f;                      // exact: ||x-x|| = 0
          const float denom = Dv + (diag ? 1.f : 0.f) + 1e-8f;
          const float rd = __builtin_amdgcn_rcpf(denom);
          const float av = dd * rd;                // a = d/denom
          const float bv = Dv * rd;                // b = D/denom
          s1 += av;
          s2 = fmaf(av, av, s2);
          s3 = fmaf(av, bv, s3);
          s4 = fmaf(bv, bv, s4);
        }
      }
    } else {
      // consume sg (keeps MFMA+dump live), D4 and rB4 (keeps loads live)
      float v = 0.f;
      #pragma unroll
      for (int c = 0; c < 16; ++c) v += sg[c * 256 + t];
      v += D4[0].x + D4[1].x + D4[2].x + D4[3].x + rB4.x;
      s1 = v;
    }

    // ---- wave shuffle reduce + block reduce, one write-set per block
    #pragma unroll
    for (int off = 32; off > 0; off >>= 1) {
      s1 += __shfl_down(s1, off);
      s2 += __shfl_down(s2, off);
      s3 += __shfl_down(s3, off);
      s4 += __shfl_down(s4, off);
    }
    float* redv = (float*)(smem + 16384);   // past the gram dump region
    if (l == 0) {
      redv[w * 4 + 0] = s1; redv[w * 4 + 1] = s2;
      redv[w * 4 + 2] = s3; redv[w * 4 + 3] = s4;
    }
    __syncthreads();
    if (t < 4) {
      const double v = (double)redv[0 * 4 + t] + (double)redv[1 * 4 + t] +
                       (double)redv[2 * 4 + t] + (double)redv[3 * 4 + t];
      const int bid = blockIdx.y * gridDim.x + blockIdx.x;
      part[t * NPART + bid] = v;
    }
  }
}

// ---------------------------------------------------------------------------
// Reduce 4 x NPART partials; emit sum(dist) = s^2*S2 - 2 s S3 + S4, s=S1/S2.
// ---------------------------------------------------------------------------
__global__ __launch_bounds__(1024) void distortion_final(
    const double* __restrict__ part, float* __restrict__ out) {
  __shared__ double red[16][4];
  const int t = threadIdx.x;
  double s[4];
  #pragma unroll
  for (int k = 0; k < 4; ++k) {
    double v = 0.0;
    #pragma unroll
    for (int c = 0; c < NPART / 1024; ++c) v += part[k * NPART + c * 1024 + t];
    s[k] = v;
  }
  #pragma unroll
  for (int off = 32; off > 0; off >>= 1)
    #pragma unroll
    for (int k = 0; k < 4; ++k) s[k] += __shfl_down(s[k], off);
  const int w = t >> 6, l = t & 63;
  if (l == 0) {
    #pragma unroll
    for (int k = 0; k < 4; ++k) red[w][k] = s[k];
  }
  __syncthreads();
  if (t == 0) {
    double S0 = 0, S1 = 0, S2 = 0, S3 = 0;
    #pragma unroll
    for (int ww = 0; ww < 16; ++ww) {
      S0 += red[ww][0]; S1 += red[ww][1]; S2 += red[ww][2]; S3 += red[ww][3];
    }
    const double sc = S0 / S1;
    const double r = (sc * sc * S1 - 2.0 * sc * S2 + S3) /
                     ((double)N_PTS * (double)N_PTS - (double)N_PTS);
    out[0] = (float)r;
  }
}

extern "C" void kernel_launch(void* const* d_in, const int* in_sizes, int n_in,
                              void* d_out, int out_size, void* d_ws, size_t ws_size,
                              hipStream_t stream) {
  const float* mapping = (const float*)d_in[0];
  const float* Dm = (const float*)d_in[1];
  float* out = (float*)d_out;
  // ws: nrm 16K | part 128K | Mhi 512K | Mlo 512K | probeA 128K | probeB 128K
  float* nrm = (float*)d_ws;
  double* part = (double*)((char*)d_ws + 16384);
  ushort* Mhi = (ushort*)((char*)d_ws + 16384 + 131072);
  ushort* Mlo = (ushort*)((char*)d_ws + 16384 + 131072 + 524288);
  double* probeA = (double*)((char*)d_ws + 16384 + 131072 + 524288 + 524288);
  double* probeB = (double*)((char*)d_ws + 16384 + 131072 + 524288 + 524288 + 131072);

  const dim3 grid(N_PTS / BT, N_PTS / BT);
  prep_kernel<<<dim3(N_PTS), dim3(64), 0, stream>>>(mapping, Mhi, Mlo, nrm);
  // production (unchanged R11 body)
  distortion_main_t<0, 1><<<grid, dim3(256), 0, stream>>>(Mhi, Mlo, Dm, nrm, part);
  distortion_final<<<1, 1024, 0, stream>>>(part, out);
  // probes (scratch outputs; visible in rocprof top-5 via REPS)
  distortion_main_t<0, 3><<<grid, dim3(256), 0, stream>>>(Mhi, Mlo, Dm, nrm, probeA);
  distortion_main_t<1, 6><<<grid, dim3(256), 0, stream>>>(Mhi, Mlo, Dm, nrm, probeB);
}

// Round 13
// 39.021 us; speedup vs baseline: 4.0979x; 4.0979x over previous
//
#include <hip/hip_runtime.h>
#include <hip/hip_bf16.h>

#define N_PTS 4096
#define D_EMB 64
#define BT    64                                   // block tile (4 waves x 32x32)
#define NWAVE ((N_PTS / BT) * (N_PTS / BT) * 4)    // 16384 wave partials

typedef __attribute__((ext_vector_type(8))) short bf16x8;  // 8 bf16 = 4 VGPR
typedef __attribute__((ext_vector_type(4))) float f32x4;   // MFMA 16x16 acc

// ---------------------------------------------------------------------------
// Prep: split f32 -> bf16 hi/lo and store in FRAGMENT-MAJOR order, so a
// wave's MFMA fragment load is  base + lane*16B  (dense 1KB per wave-instr,
// no LDS staging needed in main). Also computes exact f32 row norms.
// Layout: frag (g = row/16, ks = k/32): MhiT[((g*2+ks)*64 + lane)*8 + j]
// holds row g*16+(lane&15), k = ks*32+(lane>>4)*8+j  — identical per-lane
// mapping to the HW-verified R8 direct-load fragments.
// ---------------------------------------------------------------------------
__global__ void prep_kernel(const float* __restrict__ mapping,
                            ushort* __restrict__ MhiT,
                            ushort* __restrict__ MloT,
                            float* __restrict__ nrm) {
  const int g = blockIdx.x;           // 16-row group 0..255
  const int l = threadIdx.x;          // 0..63
  const int r16 = l & 15, kg = l >> 4;
  float s = 0.f;
  #pragma unroll
  for (int ks = 0; ks < 2; ++ks) {
    bf16x8 vh, vl;
    #pragma unroll
    for (int j = 0; j < 8; ++j) {
      const int col = ks * 32 + kg * 8 + j;
      const float x = mapping[(g * 16 + r16) * D_EMB + col];
      s = fmaf(x, x, s);
      __hip_bfloat16 h = __float2bfloat16(x);
      const float hf = __bfloat162float(h);
      __hip_bfloat16 lo = __float2bfloat16(x - hf);
      vh[j] = (short)*reinterpret_cast<ushort*>(&h);
      vl[j] = (short)*reinterpret_cast<ushort*>(&lo);
    }
    const size_t base = ((size_t)(g * 2 + ks) * 64 + l) * 8;
    *(bf16x8*)(MhiT + base) = vh;
    *(bf16x8*)(MloT + base) = vl;
  }
  // row-norm: lanes l, l+16, l+32, l+48 share row r16
  s += __shfl_xor(s, 16);
  s += __shfl_xor(s, 32);
  if (kg == 0) nrm[g * 16 + r16] = s;
}

// ---------------------------------------------------------------------------
// BARRIER-FREE main. dot = Hj.Hi + Hj.Li + Lj.Hi (absmax 0.0 since R6).
//
// R12 probes: gram-half ~14us AND epilogue-half ~14us, both ~5-10x their
// issue-work, all pipes <20% -> per-block critical path = barrier-bounded
// phases eating full load latency at 3 blocks/CU. THIS round removes the
// causes:
//  - fragments load DENSE from fragment-major MhiT/MloT (no LDS staging,
//    no staging barriers; M is 2MB -> L2-resident),
//  - gram transpose through WAVE-PRIVATE LDS (4KB/wave, XOR swizzle;
//    within-wave ds ordering needs only lgkmcnt -> NO __syncthreads
//    anywhere in the kernel),
//  - per-wave partial writes (R5: no atomics, now also no block reduce),
//  - all 16 frag loads issued up-front, then D/norms (R7 lesson) ->
//    ~20 independent VMEM in flight per wave; waves slip freely.
// acc layout (HW-verified R8): acc[m][n] = mfma(fragJ, fragI):
//   row gj = J + n*16 + kg*4 + reg, col gi = I + m*16 + r16.
// ---------------------------------------------------------------------------
__global__ __launch_bounds__(256) void distortion_main(
    const ushort* __restrict__ MhiT, const ushort* __restrict__ MloT,
    const float* __restrict__ Dm, const float* __restrict__ nrm,
    double* __restrict__ part) {
  __shared__ __align__(16) float sg[4][1024];   // wave-private 32x32 f32

  const int t = threadIdx.x;
  const int w = t >> 6, l = t & 63;
  const int r16 = l & 15, kg = l >> 4;
  const int wr = w >> 1, wc = w & 1;
  const int I = blockIdx.y * BT + wr * 32;   // wave i-rows I..I+31
  const int J = blockIdx.x * BT + wc * 32;   // wave j-rows J..J+31

  // ---- fragment loads, all up-front, dense (lane*16B)
  bf16x8 aH[2][2], aL[2][2], bH[2][2], bL[2][2];   // [ks][m/n]
  #pragma unroll
  for (int ks = 0; ks < 2; ++ks)
    #pragma unroll
    for (int m = 0; m < 2; ++m) {
      const size_t fa = (((size_t)((I >> 4) + m) * 2 + ks) * 64 + l) * 8;
      const size_t fb = (((size_t)((J >> 4) + m) * 2 + ks) * 64 + l) * 8;
      aH[ks][m] = *(const bf16x8*)(MhiT + fa);
      aL[ks][m] = *(const bf16x8*)(MloT + fa);
      bH[ks][m] = *(const bf16x8*)(MhiT + fb);
      bL[ks][m] = *(const bf16x8*)(MloT + fb);
    }

  // ---- D-tile + norms into registers, dense (8 rows x 128B per instr)
  const int jc8 = l & 7, is8 = l >> 3;
  float4 D4[4];
  float rA[4];
  #pragma unroll
  for (int it = 0; it < 4; ++it) {
    const int gi = I + it * 8 + is8;
    D4[it] = *(const float4*)(Dm + (size_t)gi * N_PTS + J + jc8 * 4);
    rA[it] = nrm[gi];
  }
  const float4 rB4 = *(const float4*)(nrm + J + jc8 * 4);

  // ---- MFMA (swapped operands)
  f32x4 acc[2][2] = {};
  #pragma unroll
  for (int ks = 0; ks < 2; ++ks)
    #pragma unroll
    for (int m = 0; m < 2; ++m)
      #pragma unroll
      for (int n = 0; n < 2; ++n) {
        acc[m][n] = __builtin_amdgcn_mfma_f32_16x16x32_bf16(
            bH[ks][n], aH[ks][m], acc[m][n], 0, 0, 0);   // Hj.Hi
        acc[m][n] = __builtin_amdgcn_mfma_f32_16x16x32_bf16(
            bH[ks][n], aL[ks][m], acc[m][n], 0, 0, 0);   // Hj.Li
        acc[m][n] = __builtin_amdgcn_mfma_f32_16x16x32_bf16(
            bL[ks][n], aH[ks][m], acc[m][n], 0, 0, 0);   // Lj.Hi
      }

  // ---- wave-private transpose: dump acc, read back row-major (no barrier;
  //      within-wave LDS ordering via lgkmcnt, compiler-inserted)
  float* sgw = sg[w];
  #pragma unroll
  for (int m = 0; m < 2; ++m) {
    const int i_loc = m * 16 + r16;
    #pragma unroll
    for (int n = 0; n < 2; ++n) {
      const int jc4 = n * 4 + kg;
      *(f32x4*)(sgw + i_loc * 32 + ((jc4 ^ (i_loc & 7)) << 2)) = acc[m][n];
    }
  }

  // ---- epilogue: gram from LDS (swizzled), D/norms from registers
  float s1 = 0.f, s2 = 0.f, s3 = 0.f, s4 = 0.f;
  #pragma unroll
  for (int it = 0; it < 4; ++it) {
    const int i_loc = it * 8 + is8;
    const int gi = I + i_loc;
    const f32x4 g4 = *(const f32x4*)(sgw + i_loc * 32 + ((jc8 ^ (i_loc & 7)) << 2));
    const float4 Dv4 = D4[it];
    #pragma unroll
    for (int r = 0; r < 4; ++r) {
      const float Dv  = (r == 0) ? Dv4.x : (r == 1) ? Dv4.y : (r == 2) ? Dv4.z : Dv4.w;
      const float rB  = (r == 0) ? rB4.x : (r == 1) ? rB4.y : (r == 2) ? rB4.z : rB4.w;
      const float dot = g4[r];
      const float sq = fmaxf(rA[it] + rB - 2.f * dot, 0.f);
      float dd = __builtin_amdgcn_sqrtf(sq);
      const bool diag = (gi == J + jc8 * 4 + r);
      if (diag) dd = 0.f;                      // exact: ||x-x|| = 0
      const float denom = Dv + (diag ? 1.f : 0.f) + 1e-8f;
      const float rd = __builtin_amdgcn_rcpf(denom);
      const float av = dd * rd;                // a = d/denom
      const float bv = Dv * rd;                // b = D/denom
      s1 += av;
      s2 = fmaf(av, av, s2);
      s3 = fmaf(av, bv, s3);
      s4 = fmaf(bv, bv, s4);
    }
  }

  // ---- wave shuffle reduce, one contention-free f64 write-set per wave
  #pragma unroll
  for (int off = 32; off > 0; off >>= 1) {
    s1 += __shfl_down(s1, off);
    s2 += __shfl_down(s2, off);
    s3 += __shfl_down(s3, off);
    s4 += __shfl_down(s4, off);
  }
  if (l == 0) {
    const int gw = ((blockIdx.y * gridDim.x + blockIdx.x) << 2) + w;
    part[0 * NWAVE + gw] = (double)s1;
    part[1 * NWAVE + gw] = (double)s2;
    part[2 * NWAVE + gw] = (double)s3;
    part[3 * NWAVE + gw] = (double)s4;
  }
}

// ---------------------------------------------------------------------------
// Reduce 4 x NWAVE partials; emit sum(dist) = s^2*S2 - 2 s S3 + S4, s=S1/S2.
// ---------------------------------------------------------------------------
__global__ __launch_bounds__(1024) void distortion_final(
    const double* __restrict__ part, float* __restrict__ out) {
  __shared__ double red[16][4];
  const int t = threadIdx.x;
  double s[4];
  #pragma unroll
  for (int k = 0; k < 4; ++k) {
    double v = 0.0;
    #pragma unroll
    for (int c = 0; c < NWAVE / 1024; ++c) v += part[k * NWAVE + c * 1024 + t];
    s[k] = v;
  }
  #pragma unroll
  for (int off = 32; off > 0; off >>= 1)
    #pragma unroll
    for (int k = 0; k < 4; ++k) s[k] += __shfl_down(s[k], off);
  const int w = t >> 6, l = t & 63;
  if (l == 0) {
    #pragma unroll
    for (int k = 0; k < 4; ++k) red[w][k] = s[k];
  }
  __syncthreads();
  if (t == 0) {
    double S0 = 0, S1 = 0, S2 = 0, S3 = 0;
    #pragma unroll
    for (int ww = 0; ww < 16; ++ww) {
      S0 += red[ww][0]; S1 += red[ww][1]; S2 += red[ww][2]; S3 += red[ww][3];
    }
    const double sc = S0 / S1;
    const double r = (sc * sc * S1 - 2.0 * sc * S2 + S3) /
                     ((double)N_PTS * (double)N_PTS - (double)N_PTS);
    out[0] = (float)r;
  }
}

extern "C" void kernel_launch(void* const* d_in, const int* in_sizes, int n_in,
                              void* d_out, int out_size, void* d_ws, size_t ws_size,
                              hipStream_t stream) {
  const float* mapping = (const float*)d_in[0];
  const float* Dm = (const float*)d_in[1];
  float* out = (float*)d_out;
  // ws layout: nrm 16KB | part 512KB | MhiT 512KB | MloT 512KB (~1.55 MB)
  float* nrm = (float*)d_ws;
  double* part = (double*)((char*)d_ws + 16384);
  ushort* MhiT = (ushort*)((char*)d_ws + 16384 + 524288);
  ushort* MloT = (ushort*)((char*)d_ws + 16384 + 524288 + 524288);

  prep_kernel<<<dim3(N_PTS / 16), dim3(64), 0, stream>>>(mapping, MhiT, MloT, nrm);
  distortion_main<<<dim3(N_PTS / BT, N_PTS / BT), dim3(256), 0, stream>>>(
      MhiT, MloT, Dm, nrm, part);
  distortion_final<<<1, 1024, 0, stream>>>(part, out);
}

// Round 14
// 30.374 us; speedup vs baseline: 5.2645x; 1.2847x over previous
//
#include <hip/hip_runtime.h>
#include <hip/hip_bf16.h>

#define N_PTS 4096
#define D_EMB 64
#define NPART 1024                                 // one partial-set per block

typedef __attribute__((ext_vector_type(8))) short bf16x8;  // 8 bf16 = 4 VGPR
typedef __attribute__((ext_vector_type(4))) float f32x4;   // MFMA 16x16 acc

// ---------------------------------------------------------------------------
// Prep (unchanged from R13, absmax 0.0 verified): split f32 -> bf16 hi/lo in
// FRAGMENT-MAJOR order (frag load = base + lane*16B, dense) + exact norms.
// ---------------------------------------------------------------------------
__global__ void prep_kernel(const float* __restrict__ mapping,
                            ushort* __restrict__ MhiT,
                            ushort* __restrict__ MloT,
                            float* __restrict__ nrm) {
  const int g = blockIdx.x;           // 16-row group 0..255
  const int l = threadIdx.x;          // 0..63
  const int r16 = l & 15, kg = l >> 4;
  float s = 0.f;
  #pragma unroll
  for (int ks = 0; ks < 2; ++ks) {
    bf16x8 vh, vl;
    #pragma unroll
    for (int j = 0; j < 8; ++j) {
      const int col = ks * 32 + kg * 8 + j;
      const float x = mapping[(g * 16 + r16) * D_EMB + col];
      s = fmaf(x, x, s);
      __hip_bfloat16 h = __float2bfloat16(x);
      const float hf = __bfloat162float(h);
      __hip_bfloat16 lo = __float2bfloat16(x - hf);
      vh[j] = (short)*reinterpret_cast<ushort*>(&h);
      vl[j] = (short)*reinterpret_cast<ushort*>(&lo);
    }
    const size_t base = ((size_t)(g * 2 + ks) * 64 + l) * 8;
    *(bf16x8*)(MhiT + base) = vh;
    *(bf16x8*)(MloT + base) = vl;
  }
  s += __shfl_xor(s, 16);
  s += __shfl_xor(s, 32);
  if (kg == 0) nrm[g * 16 + r16] = s;
}

// ---------------------------------------------------------------------------
// Multi-tile main: block = 4 waves, 64 rows x 256 cols; each wave does FOUR
// 32x32 tiles. dot = Hj.Hi + Hj.Li + Lj.Hi (absmax 0.0 since R6).
//
// R12/R13 post-mortem: per-wave fixed costs (a-frags, norms, 6-level
// shuffle reduce, partial write) paid 16384x, wave critical path ~1.3K cyc
// run once -> VALUBusy 18%, all pipes idle. THIS round amortizes:
//  - a-frags + rA loaded once per wave, then 4 unrolled j-iterations;
//  - no barriers in the loop (wave-private LDS transpose only; same-addr
//    across iters -> must-alias keeps order, within-wave DS is in-order);
//  - iter jt+1 loads hoist over iter jt epilogue (straight-line code);
//  - reduce + write once per wave; part -> 1024 sets, final reads 32KB.
// R7 lesson: loads grouped at iteration top. R5: no atomics.
// R2/R3: no min-waves launch_bounds.
// ---------------------------------------------------------------------------
__global__ __launch_bounds__(256) void distortion_main(
    const ushort* __restrict__ MhiT, const ushort* __restrict__ MloT,
    const float* __restrict__ Dm, const float* __restrict__ nrm,
    double* __restrict__ part) {
  __shared__ __align__(16) float sg[4][1024];   // wave-private 32x32 f32
  __shared__ float redv[16];                    // 4 waves x 4 sums

  const int t = threadIdx.x;
  const int w = t >> 6, l = t & 63;
  const int r16 = l & 15, kg = l >> 4;
  const int wr = w >> 1, wc = w & 1;
  const int I  = blockIdx.y * 64 + wr * 32;     // wave rows I..I+31
  const int Jb = blockIdx.x * 256 + wc * 32;    // wave col base; +jt*64
  const int jc8 = l & 7, is8 = l >> 3;

  // ---- per-wave constants: a-fragments + row norms (loaded ONCE)
  bf16x8 aH[2][2], aL[2][2];                    // [ks][m]
  #pragma unroll
  for (int ks = 0; ks < 2; ++ks)
    #pragma unroll
    for (int m = 0; m < 2; ++m) {
      const size_t fa = (((size_t)((I >> 4) + m) * 2 + ks) * 64 + l) * 8;
      aH[ks][m] = *(const bf16x8*)(MhiT + fa);
      aL[ks][m] = *(const bf16x8*)(MloT + fa);
    }
  float rA[4];
  #pragma unroll
  for (int it = 0; it < 4; ++it) rA[it] = nrm[I + it * 8 + is8];

  float* sgw = sg[w];
  float s1 = 0.f, s2 = 0.f, s3 = 0.f, s4 = 0.f;

  #pragma unroll
  for (int jt = 0; jt < 4; ++jt) {
    const int J = Jb + jt * 64;

    // ---- grouped loads for this tile (b-frags dense L2; D dense 8rx128B)
    bf16x8 bH[2][2], bL[2][2];
    #pragma unroll
    for (int ks = 0; ks < 2; ++ks)
      #pragma unroll
      for (int n = 0; n < 2; ++n) {
        const size_t fb = (((size_t)((J >> 4) + n) * 2 + ks) * 64 + l) * 8;
        bH[ks][n] = *(const bf16x8*)(MhiT + fb);
        bL[ks][n] = *(const bf16x8*)(MloT + fb);
      }
    float4 D4[4];
    #pragma unroll
    for (int it = 0; it < 4; ++it)
      D4[it] = *(const float4*)(Dm + (size_t)(I + it * 8 + is8) * N_PTS +
                                J + jc8 * 4);
    const float4 rB4 = *(const float4*)(nrm + J + jc8 * 4);

    // ---- MFMA (swapped operands; layout HW-verified)
    f32x4 acc[2][2] = {};
    #pragma unroll
    for (int ks = 0; ks < 2; ++ks)
      #pragma unroll
      for (int m = 0; m < 2; ++m)
        #pragma unroll
        for (int n = 0; n < 2; ++n) {
          acc[m][n] = __builtin_amdgcn_mfma_f32_16x16x32_bf16(
              bH[ks][n], aH[ks][m], acc[m][n], 0, 0, 0);   // Hj.Hi
          acc[m][n] = __builtin_amdgcn_mfma_f32_16x16x32_bf16(
              bH[ks][n], aL[ks][m], acc[m][n], 0, 0, 0);   // Hj.Li
          acc[m][n] = __builtin_amdgcn_mfma_f32_16x16x32_bf16(
              bL[ks][n], aH[ks][m], acc[m][n], 0, 0, 0);   // Lj.Hi
        }

    // ---- wave-private transpose (no barrier; in-order DS within wave)
    #pragma unroll
    for (int m = 0; m < 2; ++m) {
      const int i_loc = m * 16 + r16;
      #pragma unroll
      for (int n = 0; n < 2; ++n) {
        const int jc4 = n * 4 + kg;
        *(f32x4*)(sgw + i_loc * 32 + ((jc4 ^ (i_loc & 7)) << 2)) = acc[m][n];
      }
    }

    // ---- epilogue: gram from LDS, D/norms from registers
    #pragma unroll
    for (int it = 0; it < 4; ++it) {
      const int i_loc = it * 8 + is8;
      const int gi = I + i_loc;
      const f32x4 g4 =
          *(const f32x4*)(sgw + i_loc * 32 + ((jc8 ^ (i_loc & 7)) << 2));
      const float4 Dv4 = D4[it];
      #pragma unroll
      for (int r = 0; r < 4; ++r) {
        const float Dv  = (r == 0) ? Dv4.x : (r == 1) ? Dv4.y : (r == 2) ? Dv4.z : Dv4.w;
        const float rB  = (r == 0) ? rB4.x : (r == 1) ? rB4.y : (r == 2) ? rB4.z : rB4.w;
        const float dot = g4[r];
        const float sq = fmaxf(rA[it] + rB - 2.f * dot, 0.f);
        float dd = __builtin_amdgcn_sqrtf(sq);
        const bool diag = (gi == J + jc8 * 4 + r);
        if (diag) dd = 0.f;                      // exact: ||x-x|| = 0
        const float denom = Dv + (diag ? 1.f : 0.f) + 1e-8f;
        const float rd = __builtin_amdgcn_rcpf(denom);
        const float av = dd * rd;                // a = d/denom
        const float bv = Dv * rd;                // b = D/denom
        s1 += av;
        s2 = fmaf(av, av, s2);
        s3 = fmaf(av, bv, s3);
        s4 = fmaf(bv, bv, s4);
      }
    }
  }

  // ---- ONE reduce per wave, then block reduce, one write-set per block
  #pragma unroll
  for (int off = 32; off > 0; off >>= 1) {
    s1 += __shfl_down(s1, off);
    s2 += __shfl_down(s2, off);
    s3 += __shfl_down(s3, off);
    s4 += __shfl_down(s4, off);
  }
  if (l == 0) {
    redv[w * 4 + 0] = s1; redv[w * 4 + 1] = s2;
    redv[w * 4 + 2] = s3; redv[w * 4 + 3] = s4;
  }
  __syncthreads();
  if (t < 4) {
    const double v = (double)redv[0 * 4 + t] + (double)redv[1 * 4 + t] +
                     (double)redv[2 * 4 + t] + (double)redv[3 * 4 + t];
    const int bid = blockIdx.y * gridDim.x + blockIdx.x;
    part[t * NPART + bid] = v;
  }
}

// ---------------------------------------------------------------------------
// Reduce 4 x 1024 partials (32 KB); emit s^2*S2 - 2 s S3 + S4, s = S1/S2.
// ---------------------------------------------------------------------------
__global__ __launch_bounds__(1024) void distortion_final(
    const double* __restrict__ part, float* __restrict__ out) {
  __shared__ double red[16][4];
  const int t = threadIdx.x;
  double s[4];
  #pragma unroll
  for (int k = 0; k < 4; ++k) s[k] = part[k * NPART + t];
  #pragma unroll
  for (int off = 32; off > 0; off >>= 1)
    #pragma unroll
    for (int k = 0; k < 4; ++k) s[k] += __shfl_down(s[k], off);
  const int w = t >> 6, l = t & 63;
  if (l == 0) {
    #pragma unroll
    for (int k = 0; k < 4; ++k) red[w][k] = s[k];
  }
  __syncthreads();
  if (t == 0) {
    double S0 = 0, S1 = 0, S2 = 0, S3 = 0;
    #pragma unroll
    for (int ww = 0; ww < 16; ++ww) {
      S0 += red[ww][0]; S1 += red[ww][1]; S2 += red[ww][2]; S3 += red[ww][3];
    }
    const double sc = S0 / S1;
    const double r = (sc * sc * S1 - 2.0 * sc * S2 + S3) /
                     ((double)N_PTS * (double)N_PTS - (double)N_PTS);
    out[0] = (float)r;
  }
}

extern "C" void kernel_launch(void* const* d_in, const int* in_sizes, int n_in,
                              void* d_out, int out_size, void* d_ws, size_t ws_size,
                              hipStream_t stream) {
  const float* mapping = (const float*)d_in[0];
  const float* Dm = (const float*)d_in[1];
  float* out = (float*)d_out;
  // ws layout: nrm 16KB | part 32KB | MhiT 512KB | MloT 512KB (~1.07 MB)
  float* nrm = (float*)d_ws;
  double* part = (double*)((char*)d_ws + 16384);
  ushort* MhiT = (ushort*)((char*)d_ws + 16384 + 32768);
  ushort* MloT = (ushort*)((char*)d_ws + 16384 + 32768 + 524288);

  prep_kernel<<<dim3(N_PTS / 16), dim3(64), 0, stream>>>(mapping, MhiT, MloT, nrm);
  distortion_main<<<dim3(16, 64), dim3(256), 0, stream>>>(MhiT, MloT, Dm, nrm, part);
  distortion_final<<<1, 1024, 0, stream>>>(part, out);
}